// Round 20
// baseline (232.399 us; speedup 1.0000x reference)
//
#include <hip/hip_runtime.h>

// may_alias types for all LDS/global reinterpret accesses
typedef __bf16 bf16v8 __attribute__((ext_vector_type(8)));
typedef bf16v8 bf16x8 __attribute__((may_alias));
typedef unsigned int u32v2 __attribute__((ext_vector_type(2)));
typedef u32v2 u32x2 __attribute__((may_alias));
typedef unsigned short u16v8 __attribute__((ext_vector_type(8)));
typedef u16v8 u16x8 __attribute__((may_alias));
typedef unsigned short u16v;
typedef u16v u16 __attribute__((may_alias));
typedef _Float16 f16v4 __attribute__((ext_vector_type(4)));
typedef f16v4 f16x4 __attribute__((may_alias));
typedef _Float16 f16v;
typedef f16v f16s __attribute__((may_alias));
typedef float f32x4 __attribute__((ext_vector_type(4)));
typedef unsigned int u32;

#define MEMFENCE() asm volatile("" ::: "memory")

union B8 { u32 u[4]; bf16v8 v; };

__device__ __forceinline__ u32 cvtpk(float lo, float hi) {
    u32 r;
    asm("v_cvt_pk_bf16_f32 %0, %1, %2" : "=v"(r) : "v"(lo), "v"(hi));
    return r;
}

__device__ __forceinline__ unsigned short f2b(float f) {
    union { float f; unsigned u; } a; a.f = f;
    unsigned r = a.u + 0x7FFFu + ((a.u >> 16) & 1u);   // RNE
    return (unsigned short)(r >> 16);
}

// ---- weight prep: FRAGMENT-MAJOR layouts (R13-verbatim) ----
// wt  [h][m][tj][ks][lane][j]  (196608 u16): W^T[o=h*32+tj*16+(lane&15)][k=ks*32+(lane>>4)*8+j]
// wpt [h][tj][ks][lane][j]     (65536 u16):  same with Wp
__global__ void prep_weights(const float* __restrict__ Wq,
                             const float* __restrict__ Wkv,
                             const float* __restrict__ Wp,
                             const float* __restrict__ bq,
                             const float* __restrict__ bkv,
                             u16* __restrict__ wt,
                             u16* __restrict__ wpt,
                             float* __restrict__ b_all)
{
    int idx = blockIdx.x * 256 + threadIdx.x;
    if (idx < 196608) {
        int h  = idx / 24576;   int r  = idx % 24576;
        int m  = r / 8192;      int r2 = r % 8192;
        int tj = r2 / 4096;     int r3 = r2 % 4096;
        int ks = r3 / 512;      int r4 = r3 % 512;
        int lane = r4 >> 3, j = r4 & 7;
        int o = h * 32 + tj * 16 + (lane & 15);
        int k = ks * 32 + (lane >> 4) * 8 + j;
        float v = (m == 0) ? Wq[k * 256 + o]
                           : Wkv[k * 512 + (m == 1 ? o : 256 + o)];
        wt[idx] = f2b(v);
    } else if (idx < 262144) {
        int f  = idx - 196608;
        int h  = f / 8192;      int r2 = f % 8192;
        int tj = r2 / 4096;     int r3 = r2 % 4096;
        int ks = r3 / 512;      int r4 = r3 % 512;
        int lane = r4 >> 3, j = r4 & 7;
        int o = h * 32 + tj * 16 + (lane & 15);
        int k = ks * 32 + (lane >> 4) * 8 + j;
        wpt[f] = f2b(Wp[k * 256 + o]);
    } else if (idx < 262912) {
        int i = idx - 262144;
        b_all[i] = (i < 256) ? bq[i] : bkv[i - 256];
    }
}

// ================= Kernel A: QKV projection — 4 windows/block (R20) =================
// R15 structure scaled: each weight fragment feeds 8 MFMAs (4 windows x 2 token-tiles);
// per-dispatch weight L2 traffic halves again (0.78 -> 0.39 GB), per-wave MFMA chains
// double (more latency-hiding work), block count halves (less staging serialization).
// x staged per-hf: 4 win x 32 rows x 512B = 64KB -> 2 blocks/CU.
// Live regs: acc[4][2][2]=64 + wf 8 + af transient ~ 100 -> fits (512,2) 128-tier.
// All store/index formulas R15-byte-identical (win 0..3).
__global__ __launch_bounds__(512, 2)
void qkv_proj(const float* __restrict__ x,
              const u16* __restrict__ wt,
              const float* __restrict__ b_all,
              u16* __restrict__ qkv)
{
    __shared__ __align__(16) unsigned char smem[65536];
    const int b0  = blockIdx.x * 4;
    const int tid = threadIdx.x;
    const int w   = tid >> 6;
    const int l   = tid & 63;
    const int lr  = l & 15;
    const int lg  = l >> 4;

    f32x4 zero = {0.f, 0.f, 0.f, 0.f};

    const u16* whead = wt + (size_t)w * 24576;   // per-head frag block

#pragma unroll
    for (int hf = 0; hf < 2; ++hf) {
        if (hf) __syncthreads();               // all waves done reading hf=0 xs
        // ---------- stage 4 windows x 32 rows of x -> xs bf16 ----------
#pragma unroll
        for (int it = 0; it < 8; ++it) {
            int g   = it * 512 + tid;          // 0..4095 8-float groups
            int win = g >> 10;
            int r2  = g & 1023;
            int rl  = r2 >> 5;                 // row_local 0..31
            int cg  = r2 & 31;
            const float* xb = x + (size_t)(b0 + win) * 16384;
            const float4 f0 = *(const float4*)(xb + (hf * 32 + rl) * 256 + cg * 8);
            const float4 f1 = *(const float4*)(xb + (hf * 32 + rl) * 256 + cg * 8 + 4);
            u16v8 t;
            t[0] = f2b(f0.x); t[1] = f2b(f0.y); t[2] = f2b(f0.z); t[3] = f2b(f0.w);
            t[4] = f2b(f1.x); t[5] = f2b(f1.y); t[6] = f2b(f1.z); t[7] = f2b(f1.w);
            int off = win * 16384 + rl * 512 + ((cg * 16) ^ ((rl & 7) << 4));
            *(u16x8*)(smem + off) = t;
        }
        __syncthreads();

#pragma unroll
        for (int m = 0; m < 3; ++m) {          // 0=Q, 1=K, 2=V
            f32x4 acc[4][2][2];                // [win][t][tj]
#pragma unroll
            for (int win = 0; win < 4; ++win)
#pragma unroll
                for (int t = 0; t < 2; ++t)
#pragma unroll
                    for (int tj = 0; tj < 2; ++tj) acc[win][t][tj] = zero;
#pragma unroll
            for (int ks = 0; ks < 8; ++ks) {
                bf16v8 wf[2];
#pragma unroll
                for (int tj = 0; tj < 2; ++tj)
                    wf[tj] = *(const bf16x8*)(whead + m * 8192 + tj * 4096 + ks * 512 + l * 8);
#pragma unroll
                for (int win = 0; win < 4; ++win)
#pragma unroll
                    for (int t = 0; t < 2; ++t) {
                        int rl = t * 16 + lr;
                        bf16v8 af = *(const bf16x8*)(smem + win * 16384 + rl * 512 +
                                                     ((ks * 64 + lg * 16) ^ ((rl & 7) << 4)));
                        __builtin_amdgcn_s_setprio(1);
#pragma unroll
                        for (int tj = 0; tj < 2; ++tj)
                            acc[win][t][tj] = __builtin_amdgcn_mfma_f32_16x16x32_bf16(af, wf[tj], acc[win][t][tj], 0, 0, 0);
                        __builtin_amdgcn_s_setprio(0);
                    }
            }
            // +bias, write out (R15-byte-identical formulas)
#pragma unroll
            for (int win = 0; win < 4; ++win) {
                u16* base = qkv + (((size_t)(b0 + win) * 8 + w) * 3) * 2048 + m * 2048;
#pragma unroll
                for (int tj = 0; tj < 2; ++tj) {
                    float bias = b_all[m * 256 + w * 32 + tj * 16 + lr];
#pragma unroll
                    for (int t = 0; t < 2; ++t) {
                        if (m < 2) {
#pragma unroll
                            for (int e = 0; e < 4; ++e) {
                                int tok = hf * 32 + t * 16 + lg * 4 + e;
                                base[tok * 32 + tj * 16 + lr] = f2b(acc[win][t][tj][e] + bias);
                            }
                        } else {
                            int dh   = tj * 16 + lr;
                            int tok0 = hf * 32 + t * 16 + lg * 4;
                            u32x2 pv2;
                            pv2[0] = cvtpk(acc[win][t][tj][0] + bias, acc[win][t][tj][1] + bias);
                            pv2[1] = cvtpk(acc[win][t][tj][2] + bias, acc[win][t][tj][3] + bias);
                            *(u32x2*)((unsigned char*)base + dh * 128 + tok0 * 2) = pv2;
                        }
                    }
                }
            }
        }
    }
}

// ================= Kernel B: attention + output projection (R15-verbatim) =========
__global__ __launch_bounds__(512, 4)
void attn_out(const u16* __restrict__ qkv,
              const float* __restrict__ mask,
              const u16* __restrict__ wpt,
              const float* __restrict__ bp,
              float* __restrict__ out)
{
    __shared__ __align__(16) unsigned char smem[40960];
    const int b   = blockIdx.x;
    const int wdw = b & 255;
    const int tid = threadIdx.x;
    const int w   = tid >> 6;
    const int l   = tid & 63;
    const int lr  = l & 15;
    const int lg  = l >> 4;
    const int chunk = w * 4096;
    const int moff  = 32768;
    const int hc    = w * 32;
    const float scale = 0.17677669529663687f;

    f32x4 zero = {0.f, 0.f, 0.f, 0.f};

    // ---------- mask -> LDS f16 permuted ----------
    {
        const float* mb = mask + (size_t)wdw * 4096;
#pragma unroll
        for (int it = 0; it < 8; ++it) {
            int idx = it * 512 + tid;
            int q = idx >> 6, k = idx & 63;
            int colp = (k & 15) * 4 + (k >> 4);
            *(f16s*)(smem + moff + q * 128 + ((colp * 2) ^ ((q & 7) << 4)))
                = (_Float16)mb[idx];
        }
    }
    __syncthreads();   // #1

    const u16* qb  = qkv + (((size_t)b * 8 + w) * 3) * 2048;
    const u16* kb_ = qb + 2048;
    const unsigned char* vb = (const unsigned char*)(qb + 4096);

    bf16v8 aq[4], bk[4];
#pragma unroll
    for (int ti = 0; ti < 4; ++ti)
        aq[ti] = *(const bf16x8*)(qb + (ti * 16 + lr) * 32 + lg * 8);
#pragma unroll
    for (int tj = 0; tj < 4; ++tj)
        bk[tj] = *(const bf16x8*)(kb_ + (tj * 16 + lr) * 32 + lg * 8);

    // ---------- S = Q K^T + softmax ----------
    f32x4 sH[4][4];
    __builtin_amdgcn_s_setprio(1);
#pragma unroll
    for (int ti = 0; ti < 4; ++ti)
#pragma unroll
        for (int tj = 0; tj < 4; ++tj)
            sH[ti][tj] = __builtin_amdgcn_mfma_f32_16x16x32_bf16(aq[ti], bk[tj], zero, 0, 0, 0);
    __builtin_amdgcn_s_setprio(0);

#pragma unroll
    for (int ti = 0; ti < 4; ++ti)
#pragma unroll
        for (int e = 0; e < 4; ++e) {
            int row = ti * 16 + lg * 4 + e;
            f16v4 mv = *(const f16x4*)(smem + moff + row * 128 + ((lr * 8) ^ ((row & 7) << 4)));
#pragma unroll
            for (int tj = 0; tj < 4; ++tj)
                sH[ti][tj][e] = sH[ti][tj][e] * scale + (float)mv[tj];
        }
    float inv[4][4];
#pragma unroll
    for (int ti = 0; ti < 4; ++ti)
#pragma unroll
        for (int e = 0; e < 4; ++e) {
            float v0 = sH[ti][0][e], v1 = sH[ti][1][e];
            float v2 = sH[ti][2][e], v3 = sH[ti][3][e];
            float m = fmaxf(fmaxf(v0, v1), fmaxf(v2, v3));
#pragma unroll
            for (int d = 1; d < 16; d <<= 1) m = fmaxf(m, __shfl_xor(m, d));
            v0 = __expf(v0 - m); v1 = __expf(v1 - m);
            v2 = __expf(v2 - m); v3 = __expf(v3 - m);
            float s = v0 + v1 + v2 + v3;
#pragma unroll
            for (int d = 1; d < 16; d <<= 1) s += __shfl_xor(s, d);
            inv[ti][e] = 1.0f / s;
            sH[ti][0][e] = v0; sH[ti][1][e] = v1;
            sH[ti][2][e] = v2; sH[ti][3][e] = v3;
        }
    u32 pkP[4][4][2];
#pragma unroll
    for (int ti = 0; ti < 4; ++ti)
#pragma unroll
        for (int tj = 0; tj < 4; ++tj) {
            pkP[ti][tj][0] = cvtpk(sH[ti][tj][0], sH[ti][tj][1]);
            pkP[ti][tj][1] = cvtpk(sH[ti][tj][2], sH[ti][tj][3]);
        }

    // ---------- PV in two k-halves ----------
    f32x4 oH[4][2];
#pragma unroll
    for (int ti = 0; ti < 4; ++ti)
#pragma unroll
        for (int tjv = 0; tjv < 2; ++tjv) oH[ti][tjv] = zero;
#pragma unroll
    for (int kb2 = 0; kb2 < 2; ++kb2) {
#pragma unroll
        for (int ti = 0; ti < 4; ++ti)
#pragma unroll
            for (int tjh = 0; tjh < 2; ++tjh) {
                int c2 = (tjh * 16 + lr) * 2;
#pragma unroll
                for (int ep = 0; ep < 2; ++ep) {
                    u32 u = pkP[ti][2 * kb2 + tjh][ep];
                    int q0 = ti * 16 + lg * 4 + ep * 2;
                    *(u16*)(smem + chunk + q0 * 64 + (c2 ^ (((q0 >> 1) & 3) << 4))) = (unsigned short)u;
                    *(u16*)(smem + chunk + (q0 + 1) * 64 + (c2 ^ ((((q0 + 1) >> 1) & 3) << 4))) = (unsigned short)(u >> 16);
                }
            }
        MEMFENCE();
        bf16v8 bv[2];
#pragma unroll
        for (int tjv = 0; tjv < 2; ++tjv) {
            int dh = tjv * 16 + lr;
            bv[tjv] = *(const bf16x8*)(vb + dh * 128 + kb2 * 64 + lg * 16);
        }
#pragma unroll
        for (int ti = 0; ti < 4; ++ti) {
            int row = ti * 16 + lr;
            bf16v8 ap = *(const bf16x8*)(smem + chunk + row * 64 + ((lg * 16) ^ (((row >> 1) & 3) << 4)));
            __builtin_amdgcn_s_setprio(1);
#pragma unroll
            for (int tjv = 0; tjv < 2; ++tjv)
                oH[ti][tjv] = __builtin_amdgcn_mfma_f32_16x16x32_bf16(ap, bv[tjv], oH[ti][tjv], 0, 0, 0);
            __builtin_amdgcn_s_setprio(0);
        }
        MEMFENCE();
    }
#pragma unroll
    for (int ti = 0; ti < 4; ++ti)
#pragma unroll
        for (int tjv = 0; tjv < 2; ++tjv)
#pragma unroll
            for (int e = 0; e < 4; ++e)
                oH[ti][tjv][e] *= inv[ti][e];

    __syncthreads();   // #2

    // ---------- stage O -> O_lds[64][256] ----------
#pragma unroll
    for (int ti = 0; ti < 4; ++ti)
#pragma unroll
        for (int tjv = 0; tjv < 2; ++tjv)
#pragma unroll
            for (int e = 0; e < 4; ++e) {
                int row = ti * 16 + lg * 4 + e;
                int cg  = hc + tjv * 16 + lr;
                *(u16*)(smem + row * 512 + ((cg * 2) ^ ((row & 7) << 4)))
                    = f2b(oH[ti][tjv][e]);
            }
    __syncthreads();   // #3

    // ---------- output projection (frag-major wpt) ----------
    f32x4 pacc[4][2];
#pragma unroll
    for (int ti = 0; ti < 4; ++ti)
#pragma unroll
        for (int tj = 0; tj < 2; ++tj) pacc[ti][tj] = zero;
#pragma unroll
    for (int ks = 0; ks < 8; ++ks) {
        bf16v8 a_[4];
#pragma unroll
        for (int ti = 0; ti < 4; ++ti) {
            int row = ti * 16 + lr;
            a_[ti] = *(const bf16x8*)(smem + row * 512 + ((ks * 64 + lg * 16) ^ ((row & 7) << 4)));
        }
        bf16v8 bw[2];
#pragma unroll
        for (int tj = 0; tj < 2; ++tj)
            bw[tj] = *(const bf16x8*)(wpt + (size_t)w * 8192 + tj * 4096 + ks * 512 + l * 8);
        __builtin_amdgcn_s_setprio(1);
#pragma unroll
        for (int tj = 0; tj < 2; ++tj)
#pragma unroll
            for (int ti = 0; ti < 4; ++ti)
                pacc[ti][tj] = __builtin_amdgcn_mfma_f32_16x16x32_bf16(a_[ti], bw[tj], pacc[ti][tj], 0, 0, 0);
        __builtin_amdgcn_s_setprio(0);
    }
    float* ob = out + (size_t)b * 16384;
#pragma unroll
    for (int tj = 0; tj < 2; ++tj) {
        float bias = bp[hc + tj * 16 + lr];
#pragma unroll
        for (int ti = 0; ti < 4; ++ti)
#pragma unroll
            for (int e = 0; e < 4; ++e) {
                int row = ti * 16 + lg * 4 + e;
                ob[row * 256 + hc + tj * 16 + lr] = pacc[ti][tj][e] + bias;
            }
    }
}

extern "C" void kernel_launch(void* const* d_in, const int* in_sizes, int n_in,
                              void* d_out, int out_size, void* d_ws, size_t ws_size,
                              hipStream_t stream) {
    const float* x    = (const float*)d_in[0];
    const float* mask = (const float*)d_in[1];
    const float* Wq   = (const float*)d_in[2];
    const float* bq   = (const float*)d_in[3];
    const float* Wkv  = (const float*)d_in[4];
    const float* bkv  = (const float*)d_in[5];
    const float* Wp   = (const float*)d_in[6];
    const float* bp   = (const float*)d_in[7];
    float* out = (float*)d_out;

    u16*   wt    = (u16*)d_ws;                    // 196608 u16 (frag-major)
    u16*   wpt   = wt + 196608;                   // 65536 u16 (frag-major)
    float* b_all = (float*)(wpt + 65536);         // 768 f32

    const size_t qkv_off = 589824;                // bytes
    u16* qkv = (u16*)((unsigned char*)d_ws + qkv_off);

    prep_weights<<<1027, 256, 0, stream>>>(Wq, Wkv, Wp, bq, bkv, wt, wpt, b_all);
    qkv_proj<<<512, 512, 0, stream>>>(x, wt, b_all, qkv);
    attn_out<<<2048, 512, 0, stream>>>(qkv, mask, wpt, bp, out);
}

// Round 21
// 202.771 us; speedup vs baseline: 1.1461x; 1.1461x over previous
//
#include <hip/hip_runtime.h>

// may_alias types for all LDS/global reinterpret accesses
typedef __bf16 bf16v8 __attribute__((ext_vector_type(8)));
typedef bf16v8 bf16x8 __attribute__((may_alias));
typedef unsigned int u32v2 __attribute__((ext_vector_type(2)));
typedef u32v2 u32x2 __attribute__((may_alias));
typedef unsigned short u16v8 __attribute__((ext_vector_type(8)));
typedef u16v8 u16x8 __attribute__((may_alias));
typedef unsigned short u16v;
typedef u16v u16 __attribute__((may_alias));
typedef _Float16 f16v4 __attribute__((ext_vector_type(4)));
typedef f16v4 f16x4 __attribute__((may_alias));
typedef _Float16 f16v;
typedef f16v f16s __attribute__((may_alias));
typedef float f32x4 __attribute__((ext_vector_type(4)));
typedef unsigned int u32;

#define MEMFENCE() asm volatile("" ::: "memory")

union B8 { u32 u[4]; bf16v8 v; };

__device__ __forceinline__ u32 cvtpk(float lo, float hi) {
    u32 r;
    asm("v_cvt_pk_bf16_f32 %0, %1, %2" : "=v"(r) : "v"(lo), "v"(hi));
    return r;
}

__device__ __forceinline__ unsigned short f2b(float f) {
    union { float f; unsigned u; } a; a.f = f;
    unsigned r = a.u + 0x7FFFu + ((a.u >> 16) & 1u);   // RNE
    return (unsigned short)(r >> 16);
}

// ---- weight prep: FRAGMENT-MAJOR layouts (R13-validated) ----
// wt  [h][m][tj][ks][lane][j]  (196608 u16): W^T[o=h*32+tj*16+(lane&15)][k=ks*32+(lane>>4)*8+j]
// wpt [h][tj][ks][lane][j]     (65536 u16):  same with Wp
// A wave's B-frag load is base + blk*512 + l*8 -> one contiguous 1KB region per
// instruction (8 full 128B lines) — the fix that took qkv_proj 253 -> 147us.
__global__ void prep_weights(const float* __restrict__ Wq,
                             const float* __restrict__ Wkv,
                             const float* __restrict__ Wp,
                             const float* __restrict__ bq,
                             const float* __restrict__ bkv,
                             u16* __restrict__ wt,
                             u16* __restrict__ wpt,
                             float* __restrict__ b_all)
{
    int idx = blockIdx.x * 256 + threadIdx.x;
    if (idx < 196608) {
        int h  = idx / 24576;   int r  = idx % 24576;
        int m  = r / 8192;      int r2 = r % 8192;
        int tj = r2 / 4096;     int r3 = r2 % 4096;
        int ks = r3 / 512;      int r4 = r3 % 512;
        int lane = r4 >> 3, j = r4 & 7;
        int o = h * 32 + tj * 16 + (lane & 15);
        int k = ks * 32 + (lane >> 4) * 8 + j;
        float v = (m == 0) ? Wq[k * 256 + o]
                           : Wkv[k * 512 + (m == 1 ? o : 256 + o)];
        wt[idx] = f2b(v);
    } else if (idx < 262144) {
        int f  = idx - 196608;
        int h  = f / 8192;      int r2 = f % 8192;
        int tj = r2 / 4096;     int r3 = r2 % 4096;
        int ks = r3 / 512;      int r4 = r3 % 512;
        int lane = r4 >> 3, j = r4 & 7;
        int o = h * 32 + tj * 16 + (lane & 15);
        int k = ks * 32 + (lane >> 4) * 8 + j;
        wpt[f] = f2b(Wp[k * 256 + o]);
    } else if (idx < 262912) {
        int i = idx - 262144;
        b_all[i] = (i < 256) ? bq[i] : bkv[i - 256];
    }
}

// ================= Kernel A: QKV projection — 2 windows/block (R15, best: 126us) ======
// Each weight fragment feeds 4 MFMAs (2 windows x 2 token-tiles); weight L2 traffic
// halved vs 1-window. xs = 2 windows x 32KB = 64KB LDS -> 2 blocks/CU. (512,2) ->
// compiler allocates 56 VGPR, no spill (WRITE == output bytes).
__global__ __launch_bounds__(512, 2)
void qkv_proj(const float* __restrict__ x,
              const u16* __restrict__ wt,
              const float* __restrict__ b_all,
              u16* __restrict__ qkv)
{
    __shared__ __align__(16) unsigned char smem[65536];
    const int b0  = blockIdx.x * 2;
    const int tid = threadIdx.x;
    const int w   = tid >> 6;
    const int l   = tid & 63;
    const int lr  = l & 15;
    const int lg  = l >> 4;

    f32x4 zero = {0.f, 0.f, 0.f, 0.f};

    // ---------- stage 2 windows of x -> xs bf16 ----------
#pragma unroll
    for (int it = 0; it < 8; ++it) {
        int g   = it * 512 + tid;          // 0..4095 8-float groups
        int win = g >> 11;
        int r2  = g & 2047;
        int row = r2 >> 5;
        int cg  = r2 & 31;
        const float* xb = x + (size_t)(b0 + win) * 16384;
        const float4 f0 = *(const float4*)(xb + row * 256 + cg * 8);
        const float4 f1 = *(const float4*)(xb + row * 256 + cg * 8 + 4);
        u16v8 t;
        t[0] = f2b(f0.x); t[1] = f2b(f0.y); t[2] = f2b(f0.z); t[3] = f2b(f0.w);
        t[4] = f2b(f1.x); t[5] = f2b(f1.y); t[6] = f2b(f1.z); t[7] = f2b(f1.w);
        int off = win * 32768 + row * 512 + ((cg * 16) ^ ((row & 7) << 4));
        *(u16x8*)(smem + off) = t;
    }
    __syncthreads();

    const u16* whead = wt + (size_t)w * 24576;   // per-head frag block

#pragma unroll
    for (int hf = 0; hf < 2; ++hf) {
#pragma unroll
        for (int m = 0; m < 3; ++m) {            // 0=Q, 1=K, 2=V
            f32x4 acc[2][2][2];                  // [win][t][tj]
#pragma unroll
            for (int win = 0; win < 2; ++win)
#pragma unroll
                for (int t = 0; t < 2; ++t)
#pragma unroll
                    for (int tj = 0; tj < 2; ++tj) acc[win][t][tj] = zero;
#pragma unroll
            for (int ks = 0; ks < 8; ++ks) {
                bf16v8 wf[2];
#pragma unroll
                for (int tj = 0; tj < 2; ++tj)
                    wf[tj] = *(const bf16x8*)(whead + m * 8192 + tj * 4096 + ks * 512 + l * 8);
#pragma unroll
                for (int win = 0; win < 2; ++win)
#pragma unroll
                    for (int t = 0; t < 2; ++t) {
                        int row = hf * 32 + t * 16 + lr;
                        bf16v8 af = *(const bf16x8*)(smem + win * 32768 + row * 512 +
                                                     ((ks * 64 + lg * 16) ^ ((row & 7) << 4)));
                        __builtin_amdgcn_s_setprio(1);
#pragma unroll
                        for (int tj = 0; tj < 2; ++tj)
                            acc[win][t][tj] = __builtin_amdgcn_mfma_f32_16x16x32_bf16(af, wf[tj], acc[win][t][tj], 0, 0, 0);
                        __builtin_amdgcn_s_setprio(0);
                    }
            }
            // +bias, write out
#pragma unroll
            for (int win = 0; win < 2; ++win) {
                u16* base = qkv + (((size_t)(b0 + win) * 8 + w) * 3) * 2048 + m * 2048;
#pragma unroll
                for (int tj = 0; tj < 2; ++tj) {
                    float bias = b_all[m * 256 + w * 32 + tj * 16 + lr];
#pragma unroll
                    for (int t = 0; t < 2; ++t) {
                        if (m < 2) {
#pragma unroll
                            for (int e = 0; e < 4; ++e) {
                                int tok = hf * 32 + t * 16 + lg * 4 + e;
                                base[tok * 32 + tj * 16 + lr] = f2b(acc[win][t][tj][e] + bias);
                            }
                        } else {
                            int dh   = tj * 16 + lr;
                            int tok0 = hf * 32 + t * 16 + lg * 4;
                            u32x2 pv2;
                            pv2[0] = cvtpk(acc[win][t][tj][0] + bias, acc[win][t][tj][1] + bias);
                            pv2[1] = cvtpk(acc[win][t][tj][2] + bias, acc[win][t][tj][3] + bias);
                            *(u32x2*)((unsigned char*)base + dh * 128 + tok0 * 2) = pv2;
                        }
                    }
                }
            }
        }
    }
}

// ================= Kernel B: attention + output projection (validated, ~70us) =========
// Reads Q/K/V directly from the split intermediate (coalesced b128, L2/L3-hot),
// lane-contiguous f16 mask from LDS, P through per-wave LDS chunk, frag-major wpt.
__global__ __launch_bounds__(512, 4)
void attn_out(const u16* __restrict__ qkv,
              const float* __restrict__ mask,
              const u16* __restrict__ wpt,
              const float* __restrict__ bp,
              float* __restrict__ out)
{
    __shared__ __align__(16) unsigned char smem[40960];
    const int b   = blockIdx.x;
    const int wdw = b & 255;
    const int tid = threadIdx.x;
    const int w   = tid >> 6;
    const int l   = tid & 63;
    const int lr  = l & 15;
    const int lg  = l >> 4;
    const int chunk = w * 4096;
    const int moff  = 32768;
    const int hc    = w * 32;
    const float scale = 0.17677669529663687f;

    f32x4 zero = {0.f, 0.f, 0.f, 0.f};

    // ---------- mask -> LDS f16 permuted ----------
    {
        const float* mb = mask + (size_t)wdw * 4096;
#pragma unroll
        for (int it = 0; it < 8; ++it) {
            int idx = it * 512 + tid;
            int q = idx >> 6, k = idx & 63;
            int colp = (k & 15) * 4 + (k >> 4);
            *(f16s*)(smem + moff + q * 128 + ((colp * 2) ^ ((q & 7) << 4)))
                = (_Float16)mb[idx];
        }
    }
    __syncthreads();   // #1

    const u16* qb  = qkv + (((size_t)b * 8 + w) * 3) * 2048;
    const u16* kb_ = qb + 2048;
    const unsigned char* vb = (const unsigned char*)(qb + 4096);

    bf16v8 aq[4], bk[4];
#pragma unroll
    for (int ti = 0; ti < 4; ++ti)
        aq[ti] = *(const bf16x8*)(qb + (ti * 16 + lr) * 32 + lg * 8);
#pragma unroll
    for (int tj = 0; tj < 4; ++tj)
        bk[tj] = *(const bf16x8*)(kb_ + (tj * 16 + lr) * 32 + lg * 8);

    // ---------- S = Q K^T + softmax ----------
    f32x4 sH[4][4];
    __builtin_amdgcn_s_setprio(1);
#pragma unroll
    for (int ti = 0; ti < 4; ++ti)
#pragma unroll
        for (int tj = 0; tj < 4; ++tj)
            sH[ti][tj] = __builtin_amdgcn_mfma_f32_16x16x32_bf16(aq[ti], bk[tj], zero, 0, 0, 0);
    __builtin_amdgcn_s_setprio(0);

#pragma unroll
    for (int ti = 0; ti < 4; ++ti)
#pragma unroll
        for (int e = 0; e < 4; ++e) {
            int row = ti * 16 + lg * 4 + e;
            f16v4 mv = *(const f16x4*)(smem + moff + row * 128 + ((lr * 8) ^ ((row & 7) << 4)));
#pragma unroll
            for (int tj = 0; tj < 4; ++tj)
                sH[ti][tj][e] = sH[ti][tj][e] * scale + (float)mv[tj];
        }
    float inv[4][4];
#pragma unroll
    for (int ti = 0; ti < 4; ++ti)
#pragma unroll
        for (int e = 0; e < 4; ++e) {
            float v0 = sH[ti][0][e], v1 = sH[ti][1][e];
            float v2 = sH[ti][2][e], v3 = sH[ti][3][e];
            float m = fmaxf(fmaxf(v0, v1), fmaxf(v2, v3));
#pragma unroll
            for (int d = 1; d < 16; d <<= 1) m = fmaxf(m, __shfl_xor(m, d));
            v0 = __expf(v0 - m); v1 = __expf(v1 - m);
            v2 = __expf(v2 - m); v3 = __expf(v3 - m);
            float s = v0 + v1 + v2 + v3;
#pragma unroll
            for (int d = 1; d < 16; d <<= 1) s += __shfl_xor(s, d);
            inv[ti][e] = 1.0f / s;
            sH[ti][0][e] = v0; sH[ti][1][e] = v1;
            sH[ti][2][e] = v2; sH[ti][3][e] = v3;
        }
    u32 pkP[4][4][2];
#pragma unroll
    for (int ti = 0; ti < 4; ++ti)
#pragma unroll
        for (int tj = 0; tj < 4; ++tj) {
            pkP[ti][tj][0] = cvtpk(sH[ti][tj][0], sH[ti][tj][1]);
            pkP[ti][tj][1] = cvtpk(sH[ti][tj][2], sH[ti][tj][3]);
        }

    // ---------- PV in two k-halves ----------
    f32x4 oH[4][2];
#pragma unroll
    for (int ti = 0; ti < 4; ++ti)
#pragma unroll
        for (int tjv = 0; tjv < 2; ++tjv) oH[ti][tjv] = zero;
#pragma unroll
    for (int kb2 = 0; kb2 < 2; ++kb2) {
#pragma unroll
        for (int ti = 0; ti < 4; ++ti)
#pragma unroll
            for (int tjh = 0; tjh < 2; ++tjh) {
                int c2 = (tjh * 16 + lr) * 2;
#pragma unroll
                for (int ep = 0; ep < 2; ++ep) {
                    u32 u = pkP[ti][2 * kb2 + tjh][ep];
                    int q0 = ti * 16 + lg * 4 + ep * 2;
                    *(u16*)(smem + chunk + q0 * 64 + (c2 ^ (((q0 >> 1) & 3) << 4))) = (unsigned short)u;
                    *(u16*)(smem + chunk + (q0 + 1) * 64 + (c2 ^ ((((q0 + 1) >> 1) & 3) << 4))) = (unsigned short)(u >> 16);
                }
            }
        MEMFENCE();
        bf16v8 bv[2];
#pragma unroll
        for (int tjv = 0; tjv < 2; ++tjv) {
            int dh = tjv * 16 + lr;
            bv[tjv] = *(const bf16x8*)(vb + dh * 128 + kb2 * 64 + lg * 16);
        }
#pragma unroll
        for (int ti = 0; ti < 4; ++ti) {
            int row = ti * 16 + lr;
            bf16v8 ap = *(const bf16x8*)(smem + chunk + row * 64 + ((lg * 16) ^ (((row >> 1) & 3) << 4)));
            __builtin_amdgcn_s_setprio(1);
#pragma unroll
            for (int tjv = 0; tjv < 2; ++tjv)
                oH[ti][tjv] = __builtin_amdgcn_mfma_f32_16x16x32_bf16(ap, bv[tjv], oH[ti][tjv], 0, 0, 0);
            __builtin_amdgcn_s_setprio(0);
        }
        MEMFENCE();
    }
#pragma unroll
    for (int ti = 0; ti < 4; ++ti)
#pragma unroll
        for (int tjv = 0; tjv < 2; ++tjv)
#pragma unroll
            for (int e = 0; e < 4; ++e)
                oH[ti][tjv][e] *= inv[ti][e];

    __syncthreads();   // #2

    // ---------- stage O -> O_lds[64][256] ----------
#pragma unroll
    for (int ti = 0; ti < 4; ++ti)
#pragma unroll
        for (int tjv = 0; tjv < 2; ++tjv)
#pragma unroll
            for (int e = 0; e < 4; ++e) {
                int row = ti * 16 + lg * 4 + e;
                int cg  = hc + tjv * 16 + lr;
                *(u16*)(smem + row * 512 + ((cg * 2) ^ ((row & 7) << 4)))
                    = f2b(oH[ti][tjv][e]);
            }
    __syncthreads();   // #3

    // ---------- output projection (frag-major wpt) ----------
    f32x4 pacc[4][2];
#pragma unroll
    for (int ti = 0; ti < 4; ++ti)
#pragma unroll
        for (int tj = 0; tj < 2; ++tj) pacc[ti][tj] = zero;
#pragma unroll
    for (int ks = 0; ks < 8; ++ks) {
        bf16v8 a_[4];
#pragma unroll
        for (int ti = 0; ti < 4; ++ti) {
            int row = ti * 16 + lr;
            a_[ti] = *(const bf16x8*)(smem + row * 512 + ((ks * 64 + lg * 16) ^ ((row & 7) << 4)));
        }
        bf16v8 bw[2];
#pragma unroll
        for (int tj = 0; tj < 2; ++tj)
            bw[tj] = *(const bf16x8*)(wpt + (size_t)w * 8192 + tj * 4096 + ks * 512 + l * 8);
        __builtin_amdgcn_s_setprio(1);
#pragma unroll
        for (int tj = 0; tj < 2; ++tj)
#pragma unroll
            for (int ti = 0; ti < 4; ++ti)
                pacc[ti][tj] = __builtin_amdgcn_mfma_f32_16x16x32_bf16(a_[ti], bw[tj], pacc[ti][tj], 0, 0, 0);
        __builtin_amdgcn_s_setprio(0);
    }
    float* ob = out + (size_t)b * 16384;
#pragma unroll
    for (int tj = 0; tj < 2; ++tj) {
        float bias = bp[hc + tj * 16 + lr];
#pragma unroll
        for (int ti = 0; ti < 4; ++ti)
#pragma unroll
            for (int e = 0; e < 4; ++e) {
                int row = ti * 16 + lg * 4 + e;
                ob[row * 256 + hc + tj * 16 + lr] = pacc[ti][tj][e] + bias;
            }
    }
}

extern "C" void kernel_launch(void* const* d_in, const int* in_sizes, int n_in,
                              void* d_out, int out_size, void* d_ws, size_t ws_size,
                              hipStream_t stream) {
    const float* x    = (const float*)d_in[0];
    const float* mask = (const float*)d_in[1];
    const float* Wq   = (const float*)d_in[2];
    const float* bq   = (const float*)d_in[3];
    const float* Wkv  = (const float*)d_in[4];
    const float* bkv  = (const float*)d_in[5];
    const float* Wp   = (const float*)d_in[6];
    const float* bp   = (const float*)d_in[7];
    float* out = (float*)d_out;

    u16*   wt    = (u16*)d_ws;                    // 196608 u16 (frag-major)
    u16*   wpt   = wt + 196608;                   // 65536 u16 (frag-major)
    float* b_all = (float*)(wpt + 65536);         // 768 f32

    const size_t qkv_off = 589824;                // bytes
    u16* qkv = (u16*)((unsigned char*)d_ws + qkv_off);

    prep_weights<<<1027, 256, 0, stream>>>(Wq, Wkv, Wp, bq, bkv, wt, wpt, b_all);
    qkv_proj<<<1024, 512, 0, stream>>>(x, wt, b_all, qkv);
    attn_out<<<2048, 512, 0, stream>>>(qkv, mask, wpt, bp, out);
}